// Round 11
// baseline (629.118 us; speedup 1.0000x reference)
//
#include <hip/hip_runtime.h>

#define N_USERS 100000
#define N_ITEMS 50000
#define N_NODES 150000
#define EMBED   64
#define NNZV    4000000
#define BATCH   4096
// bucket = row >> 9 : 512 rows per bucket, ceil(150000/512) = 293 buckets
#define NBKT    293
// fixed staging capacity per bucket: mean 13,653 + ~21 sigma
#define CAP     16128

// ---------------- Phase A: partition edges into 512-row buckets --------------
// Record: low32 = (r&511)<<18 | col (col < 150000 < 2^18), high32 = val bits.
// R11: tile 8192 (489 blocks ~ 2/CU, was 1/CU), row[] stashed in 16 VGPRs
// across both passes (no re-read), nontemporal loads/stores (stream-once).
__global__ __launch_bounds__(512) void k_parta(
        const int* __restrict__ row, const int* __restrict__ col,
        const float* __restrict__ vals, int* __restrict__ bcnt,
        unsigned long long* __restrict__ staging, int nnz) {
    __shared__ int cnt[512];
    __shared__ int base_s[512];
    int tid = threadIdx.x;
    cnt[tid] = 0;
    __syncthreads();
    int tile0 = blockIdx.x * 8192;
    int rv[16];
    #pragma unroll
    for (int k = 0; k < 16; k++) {
        int e = tile0 + k * 512 + tid;
        rv[k] = (e < nnz) ? __builtin_nontemporal_load(row + e) : -1;
        if (rv[k] >= 0) atomicAdd(&cnt[rv[k] >> 9], 1);
    }
    __syncthreads();
    int c_ = cnt[tid];
    base_s[tid] = c_ ? (tid * CAP + atomicAdd(&bcnt[tid], c_)) : 0;
    __syncthreads();
    cnt[tid] = 0;                                       // reuse as rank counter
    __syncthreads();
    #pragma unroll
    for (int k = 0; k < 16; k++) {
        int e = tile0 + k * 512 + tid;
        int r = rv[k];
        if (r >= 0) {
            int b = r >> 9;
            int rank = atomicAdd(&cnt[b], 1);
            unsigned int cval = (unsigned int)__builtin_nontemporal_load(col + e);
            float        vval = __builtin_nontemporal_load(vals + e);
            unsigned int key = ((unsigned int)(r & 511) << 18) | cval;
            unsigned long long rec = (unsigned long long)key
                                   | ((unsigned long long)__float_as_uint(vval) << 32);
            __builtin_nontemporal_store(rec, staging + base_s[b] + rank);
        }
    }
}

// ------- Phase B: bucket scan + per-bucket histogram/scan + local scatter ----
__global__ __launch_bounds__(512) void k_partb(
        const int* __restrict__ bcnt,
        const unsigned long long* __restrict__ staging,
        int* __restrict__ row_ptr,
        unsigned long long* __restrict__ edges) {
    __shared__ int s[512];
    __shared__ int cnt[512];
    __shared__ int cur[512];
    __shared__ int base_sh;
    int b = blockIdx.x;
    int t = threadIdx.x;

    // exclusive prefix of bucket counts at position b (redundant per block, cheap)
    int v = (t < NBKT) ? bcnt[t] : 0;
    s[t] = v;
    __syncthreads();
    for (int off = 1; off < 512; off <<= 1) {
        int u = (t >= off) ? s[t - off] : 0;
        __syncthreads();
        s[t] += u;
        __syncthreads();
    }
    if (t == b) base_sh = s[t] - v;
    if (b == 0 && t == 0) row_ptr[N_NODES] = NNZV;
    __syncthreads();
    int base = base_sh;
    int n    = bcnt[b];
    const unsigned long long* sb = staging + (size_t)b * CAP;

    cnt[t] = 0;
    __syncthreads();
    for (int i = t; i < n; i += 512) {
        unsigned long long rec = __builtin_nontemporal_load(sb + i);
        atomicAdd(&cnt[(unsigned int)rec >> 18], 1);
    }
    __syncthreads();
    int c = cnt[t];
    s[t] = c;
    __syncthreads();
    for (int off = 1; off < 512; off <<= 1) {
        int u = (t >= off) ? s[t - off] : 0;
        __syncthreads();
        s[t] += u;
        __syncthreads();
    }
    int excl = s[t] - c;
    cur[t] = excl;
    int r = (b << 9) + t;
    if (r < N_NODES) row_ptr[r] = base + excl;
    __syncthreads();
    for (int i = t; i < n; i += 512) {
        unsigned long long rec = __builtin_nontemporal_load(sb + i);
        unsigned int key = (unsigned int)rec;
        int rank = atomicAdd(&cur[key >> 18], 1);
        edges[base + rank] = (rec & 0xFFFFFFFF00000000ull) | (key & 0x3FFFFu);
    }
}

// ---------------- SpMM core helper (R6-proven) -------------------------------
// Wave per row, quarter-wave (16 lanes) per edge. Inner trip count kmax is
// WAVE-UNIFORM: __shfl (ds_bpermute) from INACTIVE lanes returns 0 (round-2
// bug). Overshoot lanes hold zero-padded records (vv==0): harmless.
// R11: edge records loaded nontemporal (stream-once; keep L2 for E gathers).
__device__ __forceinline__ float4 spmm_row(const int* row_ptr,
                                           const unsigned long long* edges,
                                           const float4* __restrict__ eu4,
                                           const float4* __restrict__ ei4s, // ei4 - N_USERS*16 (pre-shifted)
                                           int r, int lane) {
    int g = lane >> 4;
    int d = lane & 15;
    int start = row_ptr[r];
    int end   = row_ptr[r + 1];
    float4 acc = make_float4(0.f, 0.f, 0.f, 0.f);
    for (int e0 = start; e0 < end; e0 += 64) {
        int ei = e0 + lane;
        unsigned long long rec = 0ull;
        if (ei < end) rec = __builtin_nontemporal_load(edges + ei);
        int clo = (int)(rec & 0xffffffffull);
        int vhi = (int)(rec >> 32);
        int nleft = end - e0;
        int kmax = (nleft + 3) >> 2;          // uniform across the wave
        #pragma unroll 4
        for (int k = 0; k < kmax; k++) {
            int src = 4 * k + g;
            int cc = __shfl(clo, src);
            float vv = __int_as_float(__shfl(vhi, src));
            const float4* basep = (cc < N_USERS) ? eu4 : ei4s;  // branchless select
            float4 e = basep[cc * 16 + d];
            acc.x += vv * e.x;
            acc.y += vv * e.y;
            acc.z += vv * e.z;
            acc.w += vv * e.w;
        }
    }
    acc.x += __shfl_xor(acc.x, 16);
    acc.y += __shfl_xor(acc.y, 16);
    acc.z += __shfl_xor(acc.z, 16);
    acc.w += __shfl_xor(acc.w, 16);
    acc.x += __shfl_xor(acc.x, 32);
    acc.y += __shfl_xor(acc.y, 32);
    acc.z += __shfl_xor(acc.z, 32);
    acc.w += __shfl_xor(acc.w, 32);
    return acc;
}

// ---------------- layer-1 SpMM: reads virtual concat(eu,ei), writes E1 -------
__global__ void k_spmm1(const int* __restrict__ row_ptr,
                        const unsigned long long* __restrict__ edges,
                        const float4* __restrict__ eu4,
                        const float4* __restrict__ ei4s,
                        float4* __restrict__ Eout) {
    int lane = threadIdx.x & 63;
    int r = blockIdx.x * 4 + (threadIdx.x >> 6);
    if (r >= N_NODES) return;
    float4 acc = spmm_row(row_ptr, edges, eu4, ei4s, r, lane);
    if (lane < 16) Eout[r * 16 + (lane & 15)] = acc;
}

// ---------------- generic SpMM: E_in -> E_out (layer 2) ----------------------
__global__ void k_spmm(const int* __restrict__ row_ptr,
                       const unsigned long long* __restrict__ edges,
                       const float4* __restrict__ Ein,
                       float4* __restrict__ Eout) {
    int lane = threadIdx.x & 63;
    int r = blockIdx.x * 4 + (threadIdx.x >> 6);
    if (r >= N_NODES) return;
    float4 acc = spmm_row(row_ptr, edges, Ein, Ein, r, lane);
    if (lane < 16) Eout[r * 16 + (lane & 15)] = acc;
}

// --------- layer-3 SpMM restricted to batch rows, fused epilogue -------------
// out[j] += 0.25*E2[r] + 0.25*E3[r]
__global__ void k_spmm_batch(const int* __restrict__ row_ptr,
                             const unsigned long long* __restrict__ edges,
                             const float4* __restrict__ Ein,   // E2
                             const int* __restrict__ bu, const int* __restrict__ bp,
                             const int* __restrict__ bn,
                             float4* __restrict__ out) {
    int lane = threadIdx.x & 63;
    int j = blockIdx.x * 4 + (threadIdx.x >> 6);
    if (j >= 3 * BATCH) return;
    int r;
    if (j < BATCH)          r = bu[j];
    else if (j < 2 * BATCH) r = N_USERS + bp[j - BATCH];
    else                    r = N_USERS + bn[j - 2 * BATCH];
    float4 acc = spmm_row(row_ptr, edges, Ein, Ein, r, lane);
    if (lane < 16) {
        float4 e2 = Ein[r * 16 + lane];
        float4 o  = out[j * 16 + lane];
        o.x += 0.25f * (acc.x + e2.x);
        o.y += 0.25f * (acc.y + e2.y);
        o.z += 0.25f * (acc.z + e2.z);
        o.w += 0.25f * (acc.w + e2.w);
        out[j * 16 + lane] = o;
    }
}

// ---------------- init gather: out = 0.25 * E0[batch] (virtual concat) -------
__global__ void k_gather_init(const int* __restrict__ bu, const int* __restrict__ bp,
                              const int* __restrict__ bn,
                              const float4* __restrict__ eu4,
                              const float4* __restrict__ ei4s,
                              float4* __restrict__ out) {
    int idx = blockIdx.x * blockDim.x + threadIdx.x;
    if (idx >= 3 * BATCH * 16) return;
    int j = idx >> 4;
    int d = idx & 15;
    int node;
    if (j < BATCH)          node = bu[j];
    else if (j < 2 * BATCH) node = N_USERS + bp[j - BATCH];
    else                    node = N_USERS + bn[j - 2 * BATCH];
    const float4* basep = (node < N_USERS) ? eu4 : ei4s;
    float4 v = basep[node * 16 + d];
    v.x *= 0.25f; v.y *= 0.25f; v.z *= 0.25f; v.w *= 0.25f;
    out[idx] = v;
}

// ---------------- accumulate gather: out += 0.25 * E[batch] ------------------
__global__ void k_gather_acc(const int* __restrict__ bu, const int* __restrict__ bp,
                             const int* __restrict__ bn, const float4* __restrict__ E,
                             float4* __restrict__ out) {
    int idx = blockIdx.x * blockDim.x + threadIdx.x;
    if (idx >= 3 * BATCH * 16) return;
    int j = idx >> 4;
    int d = idx & 15;
    int node;
    if (j < BATCH)          node = bu[j];
    else if (j < 2 * BATCH) node = N_USERS + bp[j - BATCH];
    else                    node = N_USERS + bn[j - 2 * BATCH];
    float4 v = E[node * 16 + d];
    float4 o = out[idx];
    o.x += 0.25f * v.x; o.y += 0.25f * v.y; o.z += 0.25f * v.z; o.w += 0.25f * v.w;
    out[idx] = o;
}

extern "C" void kernel_launch(void* const* d_in, const int* in_sizes, int n_in,
                              void* d_out, int out_size, void* d_ws, size_t ws_size,
                              hipStream_t stream) {
    const int*   bu   = (const int*)d_in[0];
    const int*   bp   = (const int*)d_in[1];
    const int*   bn   = (const int*)d_in[2];
    const float* eu   = (const float*)d_in[3];
    const float* ei   = (const float*)d_in[4];
    const int*   row  = (const int*)d_in[5];
    const int*   col  = (const int*)d_in[6];
    const float* vals = (const float*)d_in[7];
    float* out = (float*)d_out;

    char* p = (char*)d_ws;
    auto alloc = [&](size_t nbytes) {
        void* r = (void*)p;
        p += (nbytes + 255) & ~(size_t)255;
        return r;
    };
    float*              E_a     = (float*)alloc((size_t)N_NODES * EMBED * 4);
    float*              E_b     = (float*)alloc((size_t)N_NODES * EMBED * 4);
    unsigned long long* edges   = (unsigned long long*)alloc((size_t)NNZV * 8);
    int*                row_ptr = (int*)alloc((N_NODES + 1) * 4);
    int*                bcnt    = (int*)alloc(512 * 4);
    (void)ws_size; (void)n_in; (void)in_sizes; (void)out_size;

    // staging (NBKT*CAP*8 = 37.8 MB) overlays E_b (38.4 MB): staging is dead
    // after k_partb, before layer-2 spmm writes E_b (same stream => ordered).
    unsigned long long* staging = (unsigned long long*)E_b;

    const float4* eu4  = (const float4*)eu;
    const float4* ei4s = (const float4*)ei - (size_t)N_USERS * 16;  // pre-shifted

    const int nnz = NNZV;
    hipMemsetAsync(bcnt, 0, 512 * sizeof(int), stream);

    k_parta<<<(nnz + 8191) / 8192, 512, 0, stream>>>(row, col, vals, bcnt, staging, nnz);
    k_partb<<<NBKT, 512, 0, stream>>>(bcnt, staging, row_ptr, edges);

    // out = 0.25 * E0[batch]
    k_gather_init<<<(3 * BATCH * 16 + 255) / 256, 256, 0, stream>>>(
        bu, bp, bn, eu4, ei4s, (float4*)out);

    // layer 1: E1 = A * E0 (virtual concat input)
    k_spmm1<<<(N_NODES + 3) / 4, 256, 0, stream>>>(row_ptr, edges, eu4, ei4s, (float4*)E_a);
    k_gather_acc<<<(3 * BATCH * 16 + 255) / 256, 256, 0, stream>>>(
        bu, bp, bn, (const float4*)E_a, (float4*)out);

    // layer 2: E2 = A * E1
    k_spmm<<<(N_NODES + 3) / 4, 256, 0, stream>>>(row_ptr, edges, (const float4*)E_a, (float4*)E_b);

    // layer 3: only batch rows, fused  out += 0.25*E2[batch] + 0.25*E3[batch]
    k_spmm_batch<<<(3 * BATCH + 3) / 4, 256, 0, stream>>>(
        row_ptr, edges, (const float4*)E_b, bu, bp, bn, (float4*)out);
}

// Round 12
// 515.616 us; speedup vs baseline: 1.2201x; 1.2201x over previous
//
#include <hip/hip_runtime.h>

#define N_USERS 100000
#define N_ITEMS 50000
#define N_NODES 150000
#define EMBED   64
#define NNZV    4000000
#define BATCH   4096
// bucket = row >> 9 : 512 rows per bucket, ceil(150000/512) = 293 buckets
#define NBKT    293
// fixed staging capacity per bucket: mean 13,653 + ~21 sigma
#define CAP     16128

// ---------------- Phase A: partition edges into 512-row buckets --------------
// Record: low32 = (r&511)<<18 | col (col < 150000 < 2^18), high32 = val bits.
// NOTE (R11 lesson): NO nontemporal stores here — the staging writes are
// random-within-bucket 8B; nt bypasses L2 write-combining and explodes
// WRITE_SIZE 35->128 MB (parta 80->140 us). Regular stores let the XCD L2
// merge sibling writes of a line.
__global__ __launch_bounds__(512) void k_parta(
        const int* __restrict__ row, const int* __restrict__ col,
        const float* __restrict__ vals, int* __restrict__ bcnt,
        unsigned long long* __restrict__ staging, int nnz) {
    __shared__ int cnt[512];
    __shared__ int base_s[512];
    int tid = threadIdx.x;
    cnt[tid] = 0;
    __syncthreads();
    int tile0 = blockIdx.x * 16384;
    for (int k = 0; k < 32; k++) {
        int e = tile0 + k * 512 + tid;
        if (e < nnz) atomicAdd(&cnt[row[e] >> 9], 1);
    }
    __syncthreads();
    int c_ = cnt[tid];
    base_s[tid] = c_ ? (tid * CAP + atomicAdd(&bcnt[tid], c_)) : 0;
    __syncthreads();
    cnt[tid] = 0;                                       // reuse as rank counter
    __syncthreads();
    for (int k = 0; k < 32; k++) {
        int e = tile0 + k * 512 + tid;
        if (e < nnz) {
            int r = row[e];
            int b = r >> 9;
            int rank = atomicAdd(&cnt[b], 1);
            unsigned int key = ((unsigned int)(r & 511) << 18) | (unsigned int)col[e];
            unsigned long long rec = (unsigned long long)key
                                   | ((unsigned long long)__float_as_uint(vals[e]) << 32);
            staging[base_s[b] + rank] = rec;
        }
    }
}

// ------- Phase B: bucket scan + per-bucket histogram/scan + local scatter ----
__global__ __launch_bounds__(512) void k_partb(
        const int* __restrict__ bcnt,
        const unsigned long long* __restrict__ staging,
        int* __restrict__ row_ptr,
        unsigned long long* __restrict__ edges) {
    __shared__ int s[512];
    __shared__ int cnt[512];
    __shared__ int cur[512];
    __shared__ int base_sh;
    int b = blockIdx.x;
    int t = threadIdx.x;

    // exclusive prefix of bucket counts at position b (redundant per block, cheap)
    int v = (t < NBKT) ? bcnt[t] : 0;
    s[t] = v;
    __syncthreads();
    for (int off = 1; off < 512; off <<= 1) {
        int u = (t >= off) ? s[t - off] : 0;
        __syncthreads();
        s[t] += u;
        __syncthreads();
    }
    if (t == b) base_sh = s[t] - v;
    if (b == 0 && t == 0) row_ptr[N_NODES] = NNZV;
    __syncthreads();
    int base = base_sh;
    int n    = bcnt[b];
    const unsigned long long* sb = staging + (size_t)b * CAP;

    cnt[t] = 0;
    __syncthreads();
    for (int i = t; i < n; i += 512)
        atomicAdd(&cnt[(unsigned int)sb[i] >> 18], 1);
    __syncthreads();
    int c = cnt[t];
    s[t] = c;
    __syncthreads();
    for (int off = 1; off < 512; off <<= 1) {
        int u = (t >= off) ? s[t - off] : 0;
        __syncthreads();
        s[t] += u;
        __syncthreads();
    }
    int excl = s[t] - c;
    cur[t] = excl;
    int r = (b << 9) + t;
    if (r < N_NODES) row_ptr[r] = base + excl;
    __syncthreads();
    for (int i = t; i < n; i += 512) {
        unsigned long long rec = sb[i];
        unsigned int key = (unsigned int)rec;
        int rank = atomicAdd(&cur[key >> 18], 1);
        edges[base + rank] = (rec & 0xFFFFFFFF00000000ull) | (key & 0x3FFFFu);
    }
}

// ---------------- SpMM core helper (R6-proven) -------------------------------
// Wave per row, quarter-wave (16 lanes) per edge. Inner trip count kmax is
// WAVE-UNIFORM: __shfl (ds_bpermute) from INACTIVE lanes returns 0 (round-2
// bug). Overshoot lanes hold zero-padded records (vv==0): harmless.
// nt load on the edge stream is kept (validated: -2% spmm dur, R11); E
// gathers stay cached loads.
__device__ __forceinline__ float4 spmm_row(const int* row_ptr,
                                           const unsigned long long* edges,
                                           const float4* __restrict__ eu4,
                                           const float4* __restrict__ ei4s, // ei4 - N_USERS*16 (pre-shifted)
                                           int r, int lane) {
    int g = lane >> 4;
    int d = lane & 15;
    int start = row_ptr[r];
    int end   = row_ptr[r + 1];
    float4 acc = make_float4(0.f, 0.f, 0.f, 0.f);
    for (int e0 = start; e0 < end; e0 += 64) {
        int ei = e0 + lane;
        unsigned long long rec = 0ull;
        if (ei < end) rec = __builtin_nontemporal_load(edges + ei);
        int clo = (int)(rec & 0xffffffffull);
        int vhi = (int)(rec >> 32);
        int nleft = end - e0;
        int kmax = (nleft + 3) >> 2;          // uniform across the wave
        #pragma unroll 4
        for (int k = 0; k < kmax; k++) {
            int src = 4 * k + g;
            int cc = __shfl(clo, src);
            float vv = __int_as_float(__shfl(vhi, src));
            const float4* basep = (cc < N_USERS) ? eu4 : ei4s;  // branchless select
            float4 e = basep[cc * 16 + d];
            acc.x += vv * e.x;
            acc.y += vv * e.y;
            acc.z += vv * e.z;
            acc.w += vv * e.w;
        }
    }
    acc.x += __shfl_xor(acc.x, 16);
    acc.y += __shfl_xor(acc.y, 16);
    acc.z += __shfl_xor(acc.z, 16);
    acc.w += __shfl_xor(acc.w, 16);
    acc.x += __shfl_xor(acc.x, 32);
    acc.y += __shfl_xor(acc.y, 32);
    acc.z += __shfl_xor(acc.z, 32);
    acc.w += __shfl_xor(acc.w, 32);
    return acc;
}

// ---------------- layer-1 SpMM: reads virtual concat(eu,ei), writes E1 -------
__global__ void k_spmm1(const int* __restrict__ row_ptr,
                        const unsigned long long* __restrict__ edges,
                        const float4* __restrict__ eu4,
                        const float4* __restrict__ ei4s,
                        float4* __restrict__ Eout) {
    int lane = threadIdx.x & 63;
    int r = blockIdx.x * 4 + (threadIdx.x >> 6);
    if (r >= N_NODES) return;
    float4 acc = spmm_row(row_ptr, edges, eu4, ei4s, r, lane);
    if (lane < 16) Eout[r * 16 + (lane & 15)] = acc;
}

// ---------------- generic SpMM: E_in -> E_out (layer 2) ----------------------
__global__ void k_spmm(const int* __restrict__ row_ptr,
                       const unsigned long long* __restrict__ edges,
                       const float4* __restrict__ Ein,
                       float4* __restrict__ Eout) {
    int lane = threadIdx.x & 63;
    int r = blockIdx.x * 4 + (threadIdx.x >> 6);
    if (r >= N_NODES) return;
    float4 acc = spmm_row(row_ptr, edges, Ein, Ein, r, lane);
    if (lane < 16) Eout[r * 16 + (lane & 15)] = acc;
}

// --------- layer-3 SpMM restricted to batch rows, fused epilogue -------------
// out[j] += 0.25*E2[r] + 0.25*E3[r]
__global__ void k_spmm_batch(const int* __restrict__ row_ptr,
                             const unsigned long long* __restrict__ edges,
                             const float4* __restrict__ Ein,   // E2
                             const int* __restrict__ bu, const int* __restrict__ bp,
                             const int* __restrict__ bn,
                             float4* __restrict__ out) {
    int lane = threadIdx.x & 63;
    int j = blockIdx.x * 4 + (threadIdx.x >> 6);
    if (j >= 3 * BATCH) return;
    int r;
    if (j < BATCH)          r = bu[j];
    else if (j < 2 * BATCH) r = N_USERS + bp[j - BATCH];
    else                    r = N_USERS + bn[j - 2 * BATCH];
    float4 acc = spmm_row(row_ptr, edges, Ein, Ein, r, lane);
    if (lane < 16) {
        float4 e2 = Ein[r * 16 + lane];
        float4 o  = out[j * 16 + lane];
        o.x += 0.25f * (acc.x + e2.x);
        o.y += 0.25f * (acc.y + e2.y);
        o.z += 0.25f * (acc.z + e2.z);
        o.w += 0.25f * (acc.w + e2.w);
        out[j * 16 + lane] = o;
    }
}

// ---------------- init gather: out = 0.25 * E0[batch] (virtual concat) -------
__global__ void k_gather_init(const int* __restrict__ bu, const int* __restrict__ bp,
                              const int* __restrict__ bn,
                              const float4* __restrict__ eu4,
                              const float4* __restrict__ ei4s,
                              float4* __restrict__ out) {
    int idx = blockIdx.x * blockDim.x + threadIdx.x;
    if (idx >= 3 * BATCH * 16) return;
    int j = idx >> 4;
    int d = idx & 15;
    int node;
    if (j < BATCH)          node = bu[j];
    else if (j < 2 * BATCH) node = N_USERS + bp[j - BATCH];
    else                    node = N_USERS + bn[j - 2 * BATCH];
    const float4* basep = (node < N_USERS) ? eu4 : ei4s;
    float4 v = basep[node * 16 + d];
    v.x *= 0.25f; v.y *= 0.25f; v.z *= 0.25f; v.w *= 0.25f;
    out[idx] = v;
}

// ---------------- accumulate gather: out += 0.25 * E[batch] ------------------
__global__ void k_gather_acc(const int* __restrict__ bu, const int* __restrict__ bp,
                             const int* __restrict__ bn, const float4* __restrict__ E,
                             float4* __restrict__ out) {
    int idx = blockIdx.x * blockDim.x + threadIdx.x;
    if (idx >= 3 * BATCH * 16) return;
    int j = idx >> 4;
    int d = idx & 15;
    int node;
    if (j < BATCH)          node = bu[j];
    else if (j < 2 * BATCH) node = N_USERS + bp[j - BATCH];
    else                    node = N_USERS + bn[j - 2 * BATCH];
    float4 v = E[node * 16 + d];
    float4 o = out[idx];
    o.x += 0.25f * v.x; o.y += 0.25f * v.y; o.z += 0.25f * v.z; o.w += 0.25f * v.w;
    out[idx] = o;
}

extern "C" void kernel_launch(void* const* d_in, const int* in_sizes, int n_in,
                              void* d_out, int out_size, void* d_ws, size_t ws_size,
                              hipStream_t stream) {
    const int*   bu   = (const int*)d_in[0];
    const int*   bp   = (const int*)d_in[1];
    const int*   bn   = (const int*)d_in[2];
    const float* eu   = (const float*)d_in[3];
    const float* ei   = (const float*)d_in[4];
    const int*   row  = (const int*)d_in[5];
    const int*   col  = (const int*)d_in[6];
    const float* vals = (const float*)d_in[7];
    float* out = (float*)d_out;

    char* p = (char*)d_ws;
    auto alloc = [&](size_t nbytes) {
        void* r = (void*)p;
        p += (nbytes + 255) & ~(size_t)255;
        return r;
    };
    float*              E_a     = (float*)alloc((size_t)N_NODES * EMBED * 4);
    float*              E_b     = (float*)alloc((size_t)N_NODES * EMBED * 4);
    unsigned long long* edges   = (unsigned long long*)alloc((size_t)NNZV * 8);
    int*                row_ptr = (int*)alloc((N_NODES + 1) * 4);
    int*                bcnt    = (int*)alloc(512 * 4);
    (void)ws_size; (void)n_in; (void)in_sizes; (void)out_size;

    // staging (NBKT*CAP*8 = 37.8 MB) overlays E_b (38.4 MB): staging is dead
    // after k_partb, before layer-2 spmm writes E_b (same stream => ordered).
    unsigned long long* staging = (unsigned long long*)E_b;

    const float4* eu4  = (const float4*)eu;
    const float4* ei4s = (const float4*)ei - (size_t)N_USERS * 16;  // pre-shifted

    const int nnz = NNZV;
    hipMemsetAsync(bcnt, 0, 512 * sizeof(int), stream);

    k_parta<<<(nnz + 16383) / 16384, 512, 0, stream>>>(row, col, vals, bcnt, staging, nnz);
    k_partb<<<NBKT, 512, 0, stream>>>(bcnt, staging, row_ptr, edges);

    // out = 0.25 * E0[batch]
    k_gather_init<<<(3 * BATCH * 16 + 255) / 256, 256, 0, stream>>>(
        bu, bp, bn, eu4, ei4s, (float4*)out);

    // layer 1: E1 = A * E0 (virtual concat input)
    k_spmm1<<<(N_NODES + 3) / 4, 256, 0, stream>>>(row_ptr, edges, eu4, ei4s, (float4*)E_a);
    k_gather_acc<<<(3 * BATCH * 16 + 255) / 256, 256, 0, stream>>>(
        bu, bp, bn, (const float4*)E_a, (float4*)out);

    // layer 2: E2 = A * E1
    k_spmm<<<(N_NODES + 3) / 4, 256, 0, stream>>>(row_ptr, edges, (const float4*)E_a, (float4*)E_b);

    // layer 3: only batch rows, fused  out += 0.25*E2[batch] + 0.25*E3[batch]
    k_spmm_batch<<<(3 * BATCH + 3) / 4, 256, 0, stream>>>(
        row_ptr, edges, (const float4*)E_b, bu, bp, bn, (float4*)out);
}